// Round 9
// baseline (68.145 us; speedup 1.0000x reference)
//
#include <hip/hip_runtime.h>

#define GATE_SCALE 1.7015f

typedef __attribute__((ext_vector_type(8))) short short8;
typedef __attribute__((ext_vector_type(4))) float f32x4;
typedef __attribute__((ext_vector_type(16))) float f32x16;

__device__ __forceinline__ ushort f2bf(float f) {
    union { float f; unsigned u; } v; v.f = f;
    unsigned u = v.u;
    unsigned r = (u + 0x7FFFu + ((u >> 16) & 1u)) >> 16;
    return (ushort)r;
}

__device__ __forceinline__ void gl2lds16(const void* g, void* l) {
    __builtin_amdgcn_global_load_lds((const __attribute__((address_space(1))) void*)g,
                                     (__attribute__((address_space(3))) void*)l, 16, 0, 0);
}

// ---------------------------------------------------------------------------
// Kernel 1: convert x_cat and W to bf16; tail blocks build antisymmetrized
// complex A: Ac[n][o*8+i][2]
// ---------------------------------------------------------------------------
__global__ void convert_kernel(const float* __restrict__ xr, const float* __restrict__ xi,
                               const float* __restrict__ W,
                               const float* __restrict__ Ar, const float* __restrict__ Ai,
                               ushort* __restrict__ xc, ushort* __restrict__ wb,
                               float* __restrict__ Ac) {
    int bx = blockIdx.x;
    if (bx >= 1024) {
        int v = (bx - 1024) * 256 + threadIdx.x;   // 0..8191
        if (v < 8192) {
            int n = v >> 6, t = v & 63, o = t >> 3, i = t & 7;
            const float* arn = Ar + n * 64;
            const float* ain = Ai + n * 64;
            float a_r = 0.5f * (arn[o * 8 + i] - arn[i * 8 + o]);
            float a_i = 0.5f * (ain[o * 8 + i] + ain[i * 8 + o]);
            Ac[n * 128 + t * 2]     = a_r;
            Ac[n * 128 + t * 2 + 1] = a_i;
        }
        return;
    }
    const int XCV = 2048 * 2048 / 4;
    const int WV  = 1024 * 2048 / 4;
    const int STR = 1024 * 256;
    for (int v = bx * 256 + threadIdx.x; v < XCV + WV; v += STR) {
        float4 f;
        ushort* dst;
        if (v < XCV) {
            int idx = v * 4;
            int m = idx >> 11;
            int k = idx & 2047;
            const float* s = (k < 1024) ? (xr + m * 1024 + k) : (xi + m * 1024 + k - 1024);
            f = *(const float4*)s;
            dst = xc + idx;
        } else {
            int idx = (v - XCV) * 4;
            f = *(const float4*)(W + idx);
            dst = wb + idx;
        }
        ushort4 o;
        o.x = f2bf(f.x); o.y = f2bf(f.y); o.z = f2bf(f.z); o.w = f2bf(f.w);
        *(ushort4*)dst = o;
    }
}

// ---------------------------------------------------------------------------
// Kernel 2: GEMM gate = sigmoid((xc @ W^T + b)*1.7015) + 8-col mean -> g[2048][128]
// Tile 128x128 (halves total staged bytes to 134 MB), BK=64, 8 waves (2m x 4n),
// two 32x32x16 accs/wave. 2-slot LDS ring (4 x 16 KB), stage-first phase,
// vmcnt(0) + raw s_barrier, setprio MFMA cluster. Grid 16x8 = 128 blocks.
// XCD swizzle gives each XCD a 4m x 4n square: per-XCD working set = 4 MB
// (= L2) -> cross-block refetches are L2 hits regardless of phase drift.
// LDS XOR-swizzle via pre-swizzled global source (rule 21), 8 chunks/row.
// ---------------------------------------------------------------------------
__launch_bounds__(512, 1)
__global__ void gemm_gate_kernel(const ushort* __restrict__ A,   // xc [2048][2048]
                                 const ushort* __restrict__ Bw,  // wb [1024][2048]
                                 const float* __restrict__ bias, // [1024]
                                 float* __restrict__ g) {        // [2048][128]
    __shared__ __align__(16) ushort lA[2][128 * 64];   // 16 KB per slot
    __shared__ __align__(16) ushort lB[2][128 * 64];
    const int tid = threadIdx.x;
    const int lane = tid & 63;
    const int wid = tid >> 6;                 // 0..7
    // XCD swizzle: 128 blocks = 8 XCDs x 16; XCD x owns m-quad (x&3), n-quad
    // (x>>2): a 4x4 square of 128x128 tiles (4 MB working set = L2).
    const int bid = blockIdx.x;
    const int x = bid & 7, l = bid >> 3;      // xcd, local 0..15
    const int m0 = ((x & 3) * 4 + (l & 3)) * 128;
    const int n0 = ((x >> 2) * 4 + (l >> 2)) * 128;
    const int wm = wid >> 2, wn = wid & 3;
    const int lo = lane & 31, hi = lane >> 5, lo3 = lane & 7;
    const int arow0 = wm * 64 + lo, arow1 = wm * 64 + 32 + lo;
    const int brow = wn * 32 + lo;
    const int a07 = arow0 & 7, a17 = arow1 & 7, br7 = brow & 7;

    f32x16 acc0 = {}, acc1 = {};

    // LDS 16B-chunk s of row holds global k-chunk s ^ (row&7).
    #define STAGE(buf, k0)                                                          \
        {                                                                           \
            _Pragma("unroll")                                                       \
            for (int q = 0; q < 2; ++q) {                                           \
                int c = q * 512 + tid;                                              \
                int row = c >> 3, ks = (c & 7) ^ (row & 7);                         \
                gl2lds16(&A[(m0 + row) * 2048 + (k0) + ks * 8], &lA[buf][c * 8]);   \
            }                                                                       \
            _Pragma("unroll")                                                       \
            for (int q = 0; q < 2; ++q) {                                           \
                int c = q * 512 + tid;                                              \
                int row = c >> 3, ks = (c & 7) ^ (row & 7);                         \
                gl2lds16(&Bw[(n0 + row) * 2048 + (k0) + ks * 8], &lB[buf][c * 8]);  \
            }                                                                       \
        }

    STAGE(0, 0);
    for (int t = 0; t < 32; ++t) {
        asm volatile("s_waitcnt vmcnt(0)" ::: "memory");   // slot t&1 landed
        __builtin_amdgcn_s_barrier();                      // all waves see it
        if (t < 31) STAGE((t + 1) & 1, (t + 1) * 64);      // loads fly over phase
        const int b = t & 1;
        short8 af0[4], af1[4], bf[4];
        #pragma unroll
        for (int kk = 0; kk < 4; ++kk) {
            const int ch = 2 * kk + hi;
            af0[kk] = *(const short8*)&lA[b][arow0 * 64 + ((ch ^ a07) << 3)];
            af1[kk] = *(const short8*)&lA[b][arow1 * 64 + ((ch ^ a17) << 3)];
            bf[kk]  = *(const short8*)&lB[b][brow  * 64 + ((ch ^ br7) << 3)];
        }
        __builtin_amdgcn_s_setprio(1);
        #pragma unroll
        for (int kk = 0; kk < 4; ++kk) {
            acc0 = __builtin_amdgcn_mfma_f32_32x32x16_bf16(af0[kk], bf[kk], acc0, 0, 0, 0);
            acc1 = __builtin_amdgcn_mfma_f32_32x32x16_bf16(af1[kk], bf[kk], acc1, 0, 0, 0);
        }
        __builtin_amdgcn_s_setprio(0);
    }
    #undef STAGE

    // Epilogue: C/D col = lane&31 (n), row = (r&3)+8*(r>>2)+4*hi (m-local).
    const int ncol = n0 + wn * 32 + lo;
    const float bv = bias[ncol];
    const int gcol = ncol >> 3;
    #pragma unroll
    for (int s = 0; s < 2; ++s) {
        const f32x16 a = s ? acc1 : acc0;
        const int mb = m0 + wm * 64 + s * 32;
        #pragma unroll
        for (int r = 0; r < 16; ++r) {
            const int mrow = mb + (r & 3) + 8 * (r >> 2) + 4 * hi;
            float z = (a[r] + bv) * GATE_SCALE;
            float gate = 1.0f / (1.0f + __expf(-z));
            gate += __shfl_xor(gate, 1);
            gate += __shfl_xor(gate, 2);
            gate += __shfl_xor(gate, 4);
            if (lo3 == 0)
                g[mrow * 128 + gcol] = gate * 0.125f;
        }
    }
}

// ---------------------------------------------------------------------------
// Kernel 3: apply via Horner, zero LDS. Two lanes per site: lane h owns
// output rows h*4..h*4+3; A-block (4x8 complex) lives in 64 VGPRs, gathered
// once per block from L2-resident Ac. w-half exchanged via __shfl_xor(.,1)
// (DPP). x loads perfectly coalesced float4 (d = lane*4).
//   out = x + A(c1 x + A(c2 x + A(c3 x + A(c4 x)))),  c_k = 2(-g)^k
// ---------------------------------------------------------------------------
__launch_bounds__(256)
__global__ void apply_kernel(const float* __restrict__ xr, const float* __restrict__ xi,
                             const float* __restrict__ g,   // [2048][128]
                             const float* __restrict__ Ac,  // [128][64][2]
                             float* __restrict__ outr, float* __restrict__ outi) {
    const int tid = threadIdx.x;
    const int lane = tid & 63;
    const int wv = tid >> 6;
    const int nl = lane >> 1, h = lane & 1;
    const int n = blockIdx.x * 32 + nl;
    const int mbase = blockIdx.y * 8 + wv * 2;

    float Ar_[4][8], Ai_[4][8];
    const float* An = Ac + n * 128;
    #pragma unroll
    for (int r = 0; r < 4; ++r) {
        const int o = h * 4 + r;
        #pragma unroll
        for (int p = 0; p < 2; ++p) {
            float4 f = *(const float4*)&An[o * 16 + h * 8 + p * 4];
            Ar_[r][p * 2]     = f.x;  Ai_[r][p * 2]     = f.y;
            Ar_[r][p * 2 + 1] = f.z;  Ai_[r][p * 2 + 1] = f.w;
        }
        #pragma unroll
        for (int p = 0; p < 2; ++p) {
            float4 f = *(const float4*)&An[o * 16 + (1 - h) * 8 + p * 4];
            Ar_[r][4 + p * 2]     = f.x;  Ai_[r][4 + p * 2]     = f.y;
            Ar_[r][4 + p * 2 + 1] = f.z;  Ai_[r][4 + p * 2 + 1] = f.w;
        }
    }

    #define CMV()                                                                   \
        {                                                                           \
            float pwr[4], pwi[4];                                                   \
            _Pragma("unroll")                                                       \
            for (int k2 = 0; k2 < 4; ++k2) {                                        \
                pwr[k2] = __shfl_xor(wr[k2], 1);                                    \
                pwi[k2] = __shfl_xor(wi[k2], 1);                                    \
            }                                                                       \
            _Pragma("unroll")                                                       \
            for (int r = 0; r < 4; ++r) {                                           \
                float sr = 0.f, si = 0.f;                                           \
                _Pragma("unroll")                                                   \
                for (int jj = 0; jj < 4; ++jj) {                                    \
                    sr += Ar_[r][jj] * wr[jj]      - Ai_[r][jj] * wi[jj];           \
                    si += Ar_[r][jj] * wi[jj]      + Ai_[r][jj] * wr[jj];           \
                    sr += Ar_[r][4 + jj] * pwr[jj] - Ai_[r][4 + jj] * pwi[jj];      \
                    si += Ar_[r][4 + jj] * pwi[jj] + Ai_[r][4 + jj] * pwr[jj];      \
                }                                                                   \
                tr[r] = sr; ti[r] = si;                                             \
            }                                                                       \
        }

    #pragma unroll
    for (int mi = 0; mi < 2; ++mi) {
        const int m = mbase + mi;
        const int d = n * 8 + h * 4;
        const float4 fvr = *(const float4*)&xr[m * 1024 + d];
        const float4 fvi = *(const float4*)&xi[m * 1024 + d];
        float vr[4] = {fvr.x, fvr.y, fvr.z, fvr.w};
        float vi[4] = {fvi.x, fvi.y, fvi.z, fvi.w};
        const float gv = g[m * 128 + n];
        const float c1 = -2.f * gv, c2 = -c1 * gv, c3 = -c2 * gv, c4 = -c3 * gv;
        float wr[4], wi[4], tr[4], ti[4];

        #pragma unroll
        for (int r = 0; r < 4; ++r) { wr[r] = c4 * vr[r]; wi[r] = c4 * vi[r]; }
        CMV();
        #pragma unroll
        for (int r = 0; r < 4; ++r) { wr[r] = c3 * vr[r] + tr[r]; wi[r] = c3 * vi[r] + ti[r]; }
        CMV();
        #pragma unroll
        for (int r = 0; r < 4; ++r) { wr[r] = c2 * vr[r] + tr[r]; wi[r] = c2 * vi[r] + ti[r]; }
        CMV();
        #pragma unroll
        for (int r = 0; r < 4; ++r) { wr[r] = c1 * vr[r] + tr[r]; wi[r] = c1 * vi[r] + ti[r]; }
        CMV();

        float4 s0 = {vr[0] + tr[0], vr[1] + tr[1], vr[2] + tr[2], vr[3] + tr[3]};
        float4 s1 = {vi[0] + ti[0], vi[1] + ti[1], vi[2] + ti[2], vi[3] + ti[3]};
        *(float4*)&outr[m * 1024 + d] = s0;
        *(float4*)&outi[m * 1024 + d] = s1;
    }
    #undef CMV
}

// ---------------------------------------------------------------------------
extern "C" void kernel_launch(void* const* d_in, const int* in_sizes, int n_in,
                              void* d_out, int out_size, void* d_ws, size_t ws_size,
                              hipStream_t stream) {
    const float* xr = (const float*)d_in[0];
    const float* xi = (const float*)d_in[1];
    const float* Ar = (const float*)d_in[2];
    const float* Ai = (const float*)d_in[3];
    const float* W  = (const float*)d_in[4];
    const float* bg = (const float*)d_in[5];
    float* out = (float*)d_out;

    char* ws = (char*)d_ws;
    ushort* xc = (ushort*)(ws);                  // 8388608 B
    ushort* wb = (ushort*)(ws + 8388608);        // 4194304 B
    float*  g  = (float*) (ws + 12582912);       // 1048576 B
    float*  Ac = (float*) (ws + 13631488);       // 65536 B

    hipLaunchKernelGGL(convert_kernel, dim3(1056), dim3(256), 0, stream,
                       xr, xi, W, Ar, Ai, xc, wb, Ac);
    hipLaunchKernelGGL(gemm_gate_kernel, dim3(128), dim3(512), 0, stream, xc, wb, bg, g);
    hipLaunchKernelGGL(apply_kernel, dim3(4, 256), dim3(256), 0, stream,
                       xr, xi, g, Ac, out, out + 2 * 1024 * 1024);
}

// Round 10
// 47.514 us; speedup vs baseline: 1.4342x; 1.4342x over previous
//
#include <hip/hip_runtime.h>

#define GATE_SCALE 1.7015f

typedef __attribute__((ext_vector_type(8))) short short8;
typedef __attribute__((ext_vector_type(4))) float f32x4;
typedef __attribute__((ext_vector_type(16))) float f32x16;

__device__ __forceinline__ ushort f2bf(float f) {
    union { float f; unsigned u; } v; v.f = f;
    unsigned u = v.u;
    unsigned r = (u + 0x7FFFu + ((u >> 16) & 1u)) >> 16;
    return (ushort)r;
}

__device__ __forceinline__ void gl2lds16(const void* g, void* l) {
    __builtin_amdgcn_global_load_lds((const __attribute__((address_space(1))) void*)g,
                                     (__attribute__((address_space(3))) void*)l, 16, 0, 0);
}

// ---------------------------------------------------------------------------
// Kernel 1: convert x_cat and W to bf16; tail blocks build antisymmetrized
// complex A: Ac[n][o*8+i][2]
// ---------------------------------------------------------------------------
__global__ void convert_kernel(const float* __restrict__ xr, const float* __restrict__ xi,
                               const float* __restrict__ W,
                               const float* __restrict__ Ar, const float* __restrict__ Ai,
                               ushort* __restrict__ xc, ushort* __restrict__ wb,
                               float* __restrict__ Ac) {
    int bx = blockIdx.x;
    if (bx >= 1024) {
        int v = (bx - 1024) * 256 + threadIdx.x;   // 0..8191
        if (v < 8192) {
            int n = v >> 6, t = v & 63, o = t >> 3, i = t & 7;
            const float* arn = Ar + n * 64;
            const float* ain = Ai + n * 64;
            float a_r = 0.5f * (arn[o * 8 + i] - arn[i * 8 + o]);
            float a_i = 0.5f * (ain[o * 8 + i] + ain[i * 8 + o]);
            Ac[n * 128 + t * 2]     = a_r;
            Ac[n * 128 + t * 2 + 1] = a_i;
        }
        return;
    }
    const int XCV = 2048 * 2048 / 4;
    const int WV  = 1024 * 2048 / 4;
    const int STR = 1024 * 256;
    for (int v = bx * 256 + threadIdx.x; v < XCV + WV; v += STR) {
        float4 f;
        ushort* dst;
        if (v < XCV) {
            int idx = v * 4;
            int m = idx >> 11;
            int k = idx & 2047;
            const float* s = (k < 1024) ? (xr + m * 1024 + k) : (xi + m * 1024 + k - 1024);
            f = *(const float4*)s;
            dst = xc + idx;
        } else {
            int idx = (v - XCV) * 4;
            f = *(const float4*)(W + idx);
            dst = wb + idx;
        }
        ushort4 o;
        o.x = f2bf(f.x); o.y = f2bf(f.y); o.z = f2bf(f.z); o.w = f2bf(f.w);
        *(ushort4*)dst = o;
    }
}

// ---------------------------------------------------------------------------
// Kernel 2: GEMM gate = sigmoid((xc @ W^T + b)*1.7015) + 8-col mean -> g[2048][128]
// Tile 64x64, BK=64, 4 waves (2x2), one 32x32x16 acc/wave. Grid 512 = 2/CU.
// T3/T4: 4-slot LDS ring, prefetch depth 3, counted s_waitcnt vmcnt(8) +
// raw s_barrier. T5: setprio around MFMA. (= R7 structure, best so far.)
// NEW: XCD-rectangle swizzle — each XCD owns an 8m x 8n panel rectangle:
// per-XCD working set = 2 MB (A) + 2 MB (B) = 4 MB = its L2, so the 268 MB
// of staged refetches become L2 hits instead of HBM thrash.
// LDS XOR-swizzle via pre-swizzled global source (rule 21), 8 slots/row.
// ---------------------------------------------------------------------------
__launch_bounds__(256, 2)
__global__ void gemm_gate_kernel(const ushort* __restrict__ A,   // xc [2048][2048]
                                 const ushort* __restrict__ Bw,  // wb [1024][2048]
                                 const float* __restrict__ bias, // [1024]
                                 float* __restrict__ g) {        // [2048][128]
    __shared__ __align__(16) ushort lA[4][64 * 64];   // 4 x 8 KB
    __shared__ __align__(16) ushort lB[4][64 * 64];   // 4 x 8 KB
    const int tid = threadIdx.x;
    const int lane = tid & 63;
    const int wid = tid >> 6;                 // 0..3
    // XCD-rectangle swizzle: 512 blocks = 8 XCDs x 64. XCD x = bid&7 owns
    // m-panels [(x&3)*8, +8) x n-panels [(x>>2)*8, +8)  (panels of 64).
    const int bid = blockIdx.x;
    const int x = bid & 7, l = bid >> 3;      // xcd, local 0..63
    const int m0 = ((x & 3) * 8 + (l & 7)) * 64;
    const int n0 = ((x >> 2) * 8 + (l >> 3)) * 64;
    const int wr = wid >> 1, wc = wid & 1;
    const int lo = lane & 31, hi = lane >> 5, lo3 = lane & 7;
    const int arow = wr * 32 + lo, brow = wc * 32 + lo;
    const int ar7 = arow & 7, br7 = brow & 7;

    f32x16 acc = {};

    // LDS 16B-slot s of row holds global k-chunk s ^ (row&7).
    #define STAGE(buf, k0)                                                          \
        {                                                                           \
            _Pragma("unroll")                                                       \
            for (int q = 0; q < 2; ++q) {                                           \
                int c = q * 256 + tid;                                              \
                int row = c >> 3, ks = (c & 7) ^ (row & 7);                         \
                gl2lds16(&A[(m0 + row) * 2048 + (k0) + ks * 8], &lA[buf][c * 8]);   \
            }                                                                       \
            _Pragma("unroll")                                                       \
            for (int q = 0; q < 2; ++q) {                                           \
                int c = q * 256 + tid;                                              \
                int row = c >> 3, ks = (c & 7) ^ (row & 7);                         \
                gl2lds16(&Bw[(n0 + row) * 2048 + (k0) + ks * 8], &lB[buf][c * 8]);  \
            }                                                                       \
        }

    // Per-tile: counted vmcnt (2 stages x 4 loads in flight), raw barrier,
    // ds_read frags, issue stage(t+3) into buf (t-1)&3, MFMA cluster.
    #define TILE(t, vmstr, do_stage)                                               \
        {                                                                           \
            asm volatile("s_waitcnt vmcnt(" vmstr ")" ::: "memory");                \
            __builtin_amdgcn_s_barrier();                                           \
            const int b = (t) & 3;                                                  \
            short8 af[4], bf[4];                                                    \
            _Pragma("unroll")                                                       \
            for (int kk = 0; kk < 4; ++kk) {                                        \
                const int s0 = 2 * kk + hi;                                         \
                af[kk] = *(const short8*)&lA[b][arow * 64 + ((s0 ^ ar7) << 3)];     \
                bf[kk] = *(const short8*)&lB[b][brow * 64 + ((s0 ^ br7) << 3)];     \
            }                                                                       \
            if (do_stage) STAGE((((t) + 3) & 3), ((t) + 3) * 64);                   \
            __builtin_amdgcn_s_setprio(1);                                          \
            _Pragma("unroll")                                                       \
            for (int kk = 0; kk < 4; ++kk)                                          \
                acc = __builtin_amdgcn_mfma_f32_32x32x16_bf16(af[kk], bf[kk], acc, 0, 0, 0); \
            __builtin_amdgcn_s_setprio(0);                                          \
        }

    STAGE(0, 0);
    STAGE(1, 64);
    STAGE(2, 128);
    for (int t = 0; t < 29; ++t) TILE(t, "8", true);
    TILE(29, "8", false);
    TILE(30, "4", false);
    TILE(31, "0", false);
    #undef TILE
    #undef STAGE

    // Epilogue: C/D col = lane&31 (n), row = (r&3)+8*(r>>2)+4*hi (m-local).
    const int ncol = n0 + wc * 32 + lo;
    const float bv = bias[ncol];
    const int gcol = ncol >> 3;
    #pragma unroll
    for (int r = 0; r < 16; ++r) {
        const int mrow = m0 + wr * 32 + (r & 3) + 8 * (r >> 2) + 4 * hi;
        float z = (acc[r] + bv) * GATE_SCALE;
        float gate = 1.0f / (1.0f + __expf(-z));
        gate += __shfl_xor(gate, 1);
        gate += __shfl_xor(gate, 2);
        gate += __shfl_xor(gate, 4);
        if (lo3 == 0)
            g[mrow * 128 + gcol] = gate * 0.125f;
    }
}

// ---------------------------------------------------------------------------
// Kernel 3: apply via Horner, zero LDS. Two lanes per site: lane h owns
// output rows h*4..h*4+3; A-block (4x8 complex) lives in 64 VGPRs, gathered
// once per block from L2-resident Ac. w-half exchanged via __shfl_xor(.,1)
// (DPP). x loads perfectly coalesced float4 (d = lane*4).
//   out = x + A(c1 x + A(c2 x + A(c3 x + A(c4 x)))),  c_k = 2(-g)^k
// ---------------------------------------------------------------------------
__launch_bounds__(256)
__global__ void apply_kernel(const float* __restrict__ xr, const float* __restrict__ xi,
                             const float* __restrict__ g,   // [2048][128]
                             const float* __restrict__ Ac,  // [128][64][2]
                             float* __restrict__ outr, float* __restrict__ outi) {
    const int tid = threadIdx.x;
    const int lane = tid & 63;
    const int wv = tid >> 6;
    const int nl = lane >> 1, h = lane & 1;
    const int n = blockIdx.x * 32 + nl;
    const int mbase = blockIdx.y * 8 + wv * 2;

    float Ar_[4][8], Ai_[4][8];
    const float* An = Ac + n * 128;
    #pragma unroll
    for (int r = 0; r < 4; ++r) {
        const int o = h * 4 + r;
        #pragma unroll
        for (int p = 0; p < 2; ++p) {
            float4 f = *(const float4*)&An[o * 16 + h * 8 + p * 4];
            Ar_[r][p * 2]     = f.x;  Ai_[r][p * 2]     = f.y;
            Ar_[r][p * 2 + 1] = f.z;  Ai_[r][p * 2 + 1] = f.w;
        }
        #pragma unroll
        for (int p = 0; p < 2; ++p) {
            float4 f = *(const float4*)&An[o * 16 + (1 - h) * 8 + p * 4];
            Ar_[r][4 + p * 2]     = f.x;  Ai_[r][4 + p * 2]     = f.y;
            Ar_[r][4 + p * 2 + 1] = f.z;  Ai_[r][4 + p * 2 + 1] = f.w;
        }
    }

    #define CMV()                                                                   \
        {                                                                           \
            float pwr[4], pwi[4];                                                   \
            _Pragma("unroll")                                                       \
            for (int k2 = 0; k2 < 4; ++k2) {                                        \
                pwr[k2] = __shfl_xor(wr[k2], 1);                                    \
                pwi[k2] = __shfl_xor(wi[k2], 1);                                    \
            }                                                                       \
            _Pragma("unroll")                                                       \
            for (int r = 0; r < 4; ++r) {                                           \
                float sr = 0.f, si = 0.f;                                           \
                _Pragma("unroll")                                                   \
                for (int jj = 0; jj < 4; ++jj) {                                    \
                    sr += Ar_[r][jj] * wr[jj]      - Ai_[r][jj] * wi[jj];           \
                    si += Ar_[r][jj] * wi[jj]      + Ai_[r][jj] * wr[jj];           \
                    sr += Ar_[r][4 + jj] * pwr[jj] - Ai_[r][4 + jj] * pwi[jj];      \
                    si += Ar_[r][4 + jj] * pwi[jj] + Ai_[r][4 + jj] * pwr[jj];      \
                }                                                                   \
                tr[r] = sr; ti[r] = si;                                             \
            }                                                                       \
        }

    #pragma unroll
    for (int mi = 0; mi < 2; ++mi) {
        const int m = mbase + mi;
        const int d = n * 8 + h * 4;
        const float4 fvr = *(const float4*)&xr[m * 1024 + d];
        const float4 fvi = *(const float4*)&xi[m * 1024 + d];
        float vr[4] = {fvr.x, fvr.y, fvr.z, fvr.w};
        float vi[4] = {fvi.x, fvi.y, fvi.z, fvi.w};
        const float gv = g[m * 128 + n];
        const float c1 = -2.f * gv, c2 = -c1 * gv, c3 = -c2 * gv, c4 = -c3 * gv;
        float wr[4], wi[4], tr[4], ti[4];

        #pragma unroll
        for (int r = 0; r < 4; ++r) { wr[r] = c4 * vr[r]; wi[r] = c4 * vi[r]; }
        CMV();
        #pragma unroll
        for (int r = 0; r < 4; ++r) { wr[r] = c3 * vr[r] + tr[r]; wi[r] = c3 * vi[r] + ti[r]; }
        CMV();
        #pragma unroll
        for (int r = 0; r < 4; ++r) { wr[r] = c2 * vr[r] + tr[r]; wi[r] = c2 * vi[r] + ti[r]; }
        CMV();
        #pragma unroll
        for (int r = 0; r < 4; ++r) { wr[r] = c1 * vr[r] + tr[r]; wi[r] = c1 * vi[r] + ti[r]; }
        CMV();

        float4 s0 = {vr[0] + tr[0], vr[1] + tr[1], vr[2] + tr[2], vr[3] + tr[3]};
        float4 s1 = {vi[0] + ti[0], vi[1] + ti[1], vi[2] + ti[2], vi[3] + ti[3]};
        *(float4*)&outr[m * 1024 + d] = s0;
        *(float4*)&outi[m * 1024 + d] = s1;
    }
    #undef CMV
}

// ---------------------------------------------------------------------------
extern "C" void kernel_launch(void* const* d_in, const int* in_sizes, int n_in,
                              void* d_out, int out_size, void* d_ws, size_t ws_size,
                              hipStream_t stream) {
    const float* xr = (const float*)d_in[0];
    const float* xi = (const float*)d_in[1];
    const float* Ar = (const float*)d_in[2];
    const float* Ai = (const float*)d_in[3];
    const float* W  = (const float*)d_in[4];
    const float* bg = (const float*)d_in[5];
    float* out = (float*)d_out;

    char* ws = (char*)d_ws;
    ushort* xc = (ushort*)(ws);                  // 8388608 B
    ushort* wb = (ushort*)(ws + 8388608);        // 4194304 B
    float*  g  = (float*) (ws + 12582912);       // 1048576 B
    float*  Ac = (float*) (ws + 13631488);       // 65536 B

    hipLaunchKernelGGL(convert_kernel, dim3(1056), dim3(256), 0, stream,
                       xr, xi, W, Ar, Ai, xc, wb, Ac);
    hipLaunchKernelGGL(gemm_gate_kernel, dim3(512), dim3(256), 0, stream, xc, wb, bg, g);
    hipLaunchKernelGGL(apply_kernel, dim3(4, 256), dim3(256), 0, stream,
                       xr, xi, g, Ac, out, out + 2 * 1024 * 1024);
}